// Round 8
// baseline (831.514 us; speedup 1.0000x reference)
//
#include <hip/hip_runtime.h>
#include <hip/hip_bf16.h>
#include <hip/hip_cooperative_groups.h>

namespace cg = cooperative_groups;

// AttentionPoolingAdvance: B=8,S=2048,D=768 (fp32 in/out, detected on device).
// out[b] = mean_q softmax((Q K^T)/sqrt(D), key-mask) V
// Algebra: out = (c^T x) Wv^T + bv with c_k=(1/S) sum_q w[q,k];
// score[q,k] == (z_q.x_k)/sqrt(D) + beta_k modulo softmax-invariant terms,
// z = x @ (Wq^T Wk), beta_k = x_k.(Wk^T bq)/sqrt(D); bk cancels.
// Round 8: single cooperative mega-kernel (grid.sync between phases) to kill
// ~135us of inter-dispatch overhead. Fallback to round-7 multi-kernel path if
// cooperative launch is unavailable.

#define S 2048
#define DIM 768
#define BATCH 8

typedef __hip_bfloat16 bf16;
typedef __attribute__((ext_vector_type(8))) short bf16x8;
typedef __attribute__((ext_vector_type(4))) short short4v;
typedef __attribute__((ext_vector_type(4))) float f32x4;

__device__ __forceinline__ f32x4 mfma16(bf16x8 a, bf16x8 b, f32x4 c) {
  return __builtin_amdgcn_mfma_f32_16x16x32_bf16(a, b, c, 0, 0, 0);
}

__device__ __forceinline__ void load_lds16(const short* g, short* l) {
  __builtin_amdgcn_global_load_lds(
      (const __attribute__((address_space(1))) unsigned int*)g,
      (__attribute__((address_space(3))) unsigned int*)l, 16, 0, 0);
}

__device__ __forceinline__ float b2f(short u) {
  union { float f; unsigned u; } v;
  v.u = ((unsigned)(unsigned short)u) << 16;
  return v.f;
}

__device__ __forceinline__ short f2b(float f) {
  bf16 h = __float2bfloat16(f);
  return *(short*)&h;
}

#define INV_SCALE 0.03608439182435161f  // 1/sqrt(768)

// ---------------- shared tile-GEMM core (m97-style, 128x128, BK=32) --------
__device__ __forceinline__ void tile_kloop(const short* __restrict__ Abase,
                                           const short* __restrict__ Bbase,
                                           short* As, short* Bs, int mblk,
                                           int nblk, int tid,
                                           f32x4 (&acc)[4][4]) {
  const int lane = tid & 63;
  const int lr = lane & 15, quad = lane >> 4;
  const int wave = tid >> 6;
  const int wm = (wave >> 1) * 64, wn = (wave & 1) * 64;
  const int c0row = tid >> 2, colw = (tid & 3) * 8;
  const short* Ag0 = Abase + (long)(mblk + c0row) * DIM + colw;
  const short* Ag1 = Abase + (long)(mblk + 64 + c0row) * DIM + colw;
  const short* Bg0 = Bbase + (long)(nblk + c0row) * DIM + colw;
  const short* Bg1 = Bbase + (long)(nblk + 64 + c0row) * DIM + colw;
  short* Al0 = As + tid * 8;
  short* Al1 = As + 2048 + tid * 8;
  short* Bl0 = Bs + tid * 8;
  short* Bl1 = Bs + 2048 + tid * 8;
  for (int k0 = 0; k0 < DIM; k0 += 32) {
    load_lds16(Ag0 + k0, Al0);
    load_lds16(Ag1 + k0, Al1);
    load_lds16(Bg0 + k0, Bl0);
    load_lds16(Bg1 + k0, Bl1);
    asm volatile("s_waitcnt vmcnt(0)" ::: "memory");
    __syncthreads();
    bf16x8 af[4], bfr[4];
#pragma unroll
    for (int it = 0; it < 4; ++it)
      af[it] = *(const bf16x8*)(As + (wm + it * 16 + lr) * 32 + quad * 8);
#pragma unroll
    for (int jt = 0; jt < 4; ++jt)
      bfr[jt] = *(const bf16x8*)(Bs + (wn + jt * 16 + lr) * 32 + quad * 8);
#pragma unroll
    for (int it = 0; it < 4; ++it)
#pragma unroll
      for (int jt = 0; jt < 4; ++jt)
        acc[it][jt] = mfma16(af[it], bfr[jt], acc[it][jt]);
    __syncthreads();
  }
}

__device__ __forceinline__ void tile_store(short* __restrict__ D, int mblk,
                                           int nblk, int tid,
                                           f32x4 (&acc)[4][4]) {
  const int lane = tid & 63, lr = lane & 15, quad = lane >> 4;
  const int wave = tid >> 6, wm = (wave >> 1) * 64, wn = (wave & 1) * 64;
#pragma unroll
  for (int it = 0; it < 4; ++it)
#pragma unroll
    for (int jt = 0; jt < 4; ++jt)
#pragma unroll
      for (int r = 0; r < 4; ++r)
        D[(long)(mblk + wm + it * 16 + quad * 4 + r) * DIM + nblk + wn +
          jt * 16 + lr] = f2b(acc[it][jt][r]);
}

// -------- device sub-routines shared by mega kernel and fallback ----------
__device__ __forceinline__ void do_transpose_job(const void* src, short* dstT,
                                                 int r, int f, int tid,
                                                 char* smem) {
  unsigned short(*tile)[66] = (unsigned short(*)[66])smem;
  unsigned short* dst = (unsigned short*)dstT;
  const int obase = (r / 12) * 64, ibase = (r % 12) * 64;
  const int col = tid & 63, rq = tid >> 6;
#pragma unroll
  for (int rr = 0; rr < 64; rr += 4) {
    const long idx = (long)(obase + rr + rq) * DIM + ibase + col;
    const float v = f ? ((const float*)src)[idx] : b2f(((const short*)src)[idx]);
    tile[rr + rq][col] = (unsigned short)f2b(v);
  }
  __syncthreads();
#pragma unroll
  for (int rr = 0; rr < 64; rr += 4)
    dst[(long)(ibase + rr + rq) * DIM + obase + col] = tile[col][rr + rq];
  __syncthreads();
}

__device__ __forceinline__ void do_bvec_job(const void* Wk_raw,
                                            const void* bq_raw,
                                            float* __restrict__ bvec, int slice,
                                            int f, int tid, float* red) {
  const int jj = slice * 128 + (tid & 127);
  const int half = tid >> 7;
  float s = 0.f;
  if (f) {
    const float* W = (const float*)Wk_raw;
    const float* bq = (const float*)bq_raw;
    for (int o = half; o < DIM; o += 2) s += W[(long)o * DIM + jj] * bq[o];
  } else {
    const short* W = (const short*)Wk_raw;
    const short* bq = (const short*)bq_raw;
    for (int o = half; o < DIM; o += 2) s += b2f(W[(long)o * DIM + jj]) * b2f(bq[o]);
  }
  red[tid] = s;
  __syncthreads();
  if (tid < 128) bvec[jj] = red[tid] + red[tid + 128];
  __syncthreads();
}

__device__ __forceinline__ void do_convert_job(const void* x_raw,
                                               const int* mask,
                                               const float* bvec, short* xb,
                                               float* betas, int n, int f,
                                               int tid) {
  const int lane = tid & 63;
  short* xo = xb + (long)n * DIM;
  float s = 0.f;
  if (f) {
    const float4* x4 = (const float4*)((const float*)x_raw + (long)n * DIM);
    const float4* bv4 = (const float4*)bvec;
#pragma unroll
    for (int it = 0; it < 3; ++it) {
      const int idx = it * 64 + lane;
      const float4 v = x4[idx];
      const float4 bb = bv4[idx];
      short4v sv = {f2b(v.x), f2b(v.y), f2b(v.z), f2b(v.w)};
      *(short4v*)(xo + idx * 4) = sv;
      s += v.x * bb.x + v.y * bb.y + v.z * bb.z + v.w * bb.w;
    }
  } else {
    const short4v* x4 = (const short4v*)((const short*)x_raw + (long)n * DIM);
    const float4* bv4 = (const float4*)bvec;
#pragma unroll
    for (int it = 0; it < 3; ++it) {
      const int idx = it * 64 + lane;
      const short4v v = x4[idx];
      const float4 bb = bv4[idx];
      *(short4v*)(xo + idx * 4) = v;
      s += b2f(v.x) * bb.x + b2f(v.y) * bb.y + b2f(v.z) * bb.z + b2f(v.w) * bb.w;
    }
  }
#pragma unroll
  for (int off = 1; off < 64; off <<= 1) s += __shfl_xor(s, off, 64);
  if (lane == 0) betas[n] = mask[n] ? s * INV_SCALE : -1e30f;
}

__device__ __forceinline__ void score_epilogue(const float* betas, float* l_out,
                                               short* Eb, int b, int mblk,
                                               int nblk, int tid,
                                               f32x4 (&acc)[4][4]) {
  const int lane = tid & 63, lr = lane & 15, quad = lane >> 4;
  const int wave = tid >> 6, wm = (wave >> 1) * 64, wn = (wave & 1) * 64;
  float bet[4];
#pragma unroll
  for (int jt = 0; jt < 4; ++jt)
    bet[jt] = betas[b * S + nblk + wn + jt * 16 + lr];
  float* lrow = l_out + b * S;
#pragma unroll
  for (int it = 0; it < 4; ++it) {
#pragma unroll
    for (int r = 0; r < 4; ++r) {
      const int q = mblk + wm + it * 16 + quad * 4 + r;
      float s = 0.f;
#pragma unroll
      for (int jt = 0; jt < 4; ++jt) {
        float e = __expf(fminf(acc[it][jt][r] * INV_SCALE + bet[jt], 60.f));
        s += e;
        Eb[(long)q * S + nblk + wn + jt * 16 + lr] = f2b(e);
      }
      s += __shfl_xor(s, 1, 64);
      s += __shfl_xor(s, 2, 64);
      s += __shfl_xor(s, 4, 64);
      s += __shfl_xor(s, 8, 64);
      if (lr == 0) atomicAdd(&lrow[q], s);
    }
  }
}

__device__ __forceinline__ void do_reduce_job(const short* Eb, const float* lrow,
                                              float* crow, int q0, int tid) {
  const int k8 = tid * 8;
  float acc[8] = {};
#pragma unroll
  for (int q = q0; q < q0 + 16; ++q) {
    bf16x8 ev = *(const bf16x8*)(Eb + (long)q * S + k8);
    const float lv = lrow[q];
    const float rq = lv > 0.f ? 1.0f / lv : 0.f;
#pragma unroll
    for (int j = 0; j < 8; ++j) acc[j] += b2f(ev[j]) * rq;
  }
#pragma unroll
  for (int j = 0; j < 8; ++j)
    atomicAdd(&crow[k8 + j], acc[j] * (1.0f / 2048.0f));
}

__device__ __forceinline__ void do_y_job(const short* xb, const float* c,
                                         float* y, int b, int kc, int ic,
                                         int tid) {
  const int i = ic * 256 + tid;
  const int kstart = kc * 128;
  const short* xr = xb + (long)(b * S + kstart) * DIM + i;
  const float* cb = c + b * S + kstart;
  float acc = 0.f;
  for (int k = 0; k < 128; ++k) acc += cb[k] * b2f(xr[(long)k * DIM]);
  atomicAdd(&y[b * DIM + i], acc);
}

__device__ __forceinline__ void do_out_job(const float* y, const void* Wv_raw,
                                           const void* bv_raw, void* out, int w,
                                           int f, int tid) {
  const int lane = tid & 63;
  const int b = w / DIM, o = w % DIM;
  const float4* y4 = (const float4*)(y + (long)b * DIM);
  float s = 0.f;
  if (f) {
    const float4* wr = (const float4*)((const float*)Wv_raw + (long)o * DIM);
#pragma unroll
    for (int it = 0; it < 3; ++it) {
      const int idx = it * 64 + lane;
      const float4 a = y4[idx], wv = wr[idx];
      s += a.x * wv.x + a.y * wv.y + a.z * wv.z + a.w * wv.w;
    }
  } else {
    const short4v* wr = (const short4v*)((const short*)Wv_raw + (long)o * DIM);
#pragma unroll
    for (int it = 0; it < 3; ++it) {
      const int idx = it * 64 + lane;
      const float4 a = y4[idx];
      const short4v wv = wr[idx];
      s += a.x * b2f(wv.x) + a.y * b2f(wv.y) + a.z * b2f(wv.z) + a.w * b2f(wv.w);
    }
  }
#pragma unroll
  for (int off = 1; off < 64; off <<= 1) s += __shfl_xor(s, off, 64);
  if (lane == 0) {
    const float bias = f ? ((const float*)bv_raw)[o] : b2f(((const short*)bv_raw)[o]);
    const float v = s + bias;
    if (f) ((float*)out)[b * DIM + o] = v;
    else ((bf16*)out)[b * DIM + o] = __float2bfloat16(v);
  }
}

// ============================ mega kernel ================================
struct MegaArgs {
  const void* x_raw; const int* mask;
  const void* Wq_raw; const void* bq_raw; const void* Wk_raw;
  const void* Wv_raw; const void* bv_raw;
  void* out;
  short* xb; short* WqT; short* WkT; short* Mt;
  float* betas; float* bvec; float* lcy;  // l,c,y contiguous (38912 floats)
  short* z; short* E;
  int nb, rounds;
};

__global__ __launch_bounds__(256, 4) void mega(MegaArgs a) {
  cg::grid_group grid = cg::this_grid();
  __shared__ __align__(16) char smem[17664];
  short* As = (short*)smem;
  short* Bs = (short*)(smem + 8192);
  float* red = (float*)(smem + 16384);
  const int tid = threadIdx.x;
  const int nblocks = gridDim.x;
  float* l = a.lcy;
  float* c = a.lcy + 16384;
  float* y = a.lcy + 32768;

  // per-block dtype detect (deterministic, no cross-block comm needed)
  int bad = 0;
  {
    const unsigned short* xs = (const unsigned short*)a.x_raw;
    for (int i = tid; i < 2048; i += 256) {
      int e = (xs[i] >> 7) & 0xFF;
      if (e < 0x60 || e >= 0x9F) bad = 1;
    }
    if (tid == 0) *(int*)(smem + 17408) = 0;
    __syncthreads();
    if (__any(bad) && (tid & 63) == 0) atomicOr((int*)(smem + 17408), 1);
    __syncthreads();
  }
  const int f = *(int*)(smem + 17408);
  __syncthreads();

  // Phase A: W transposes (288 jobs) + bvec slices (6 jobs)
  for (int j = blockIdx.x; j < 294; j += nblocks) {
    if (j < 288) {
      do_transpose_job(j < 144 ? a.Wq_raw : a.Wk_raw,
                       j < 144 ? a.WqT : a.WkT, j % 144, f, tid, smem);
    } else {
      do_bvec_job(a.Wk_raw, a.bq_raw, a.bvec, j - 288, f, tid, red);
    }
  }
  grid.sync();

  // Phase B: Mt GEMM (36) + x convert/beta (4096) + zero l/c/y (10)
  for (int j = blockIdx.x; j < 4142; j += nblocks) {
    if (j < 36) {
      f32x4 acc[4][4] = {};
      tile_kloop(a.WkT, a.WqT, As, Bs, (j / 6) * 128, (j % 6) * 128, tid, acc);
      tile_store(a.Mt, (j / 6) * 128, (j % 6) * 128, tid, acc);
    } else if (j < 4132) {
      const int n = (j - 36) * 4 + (tid >> 6);
      do_convert_job(a.x_raw, a.mask, a.bvec, a.xb, a.betas, n, f, tid);
    } else {
      const int base = (j - 4132) * 4096;
      for (int i = tid; i < 4096; i += 256) {
        const int idx = base + i;
        if (idx < 38912) a.lcy[idx] = 0.f;
      }
    }
  }
  grid.sync();

  for (int r = 0; r < a.rounds; ++r) {
    const int b0 = r * a.nb;
    // Phase C: z = x @ M  (nb*16 x 6 tiles)
    const int njC = a.nb * 96;
    for (int j = blockIdx.x; j < njC; j += nblocks) {
      const int mblk = (j / 6) * 128, nblk = (j % 6) * 128;
      f32x4 acc[4][4] = {};
      tile_kloop(a.xb + (long)b0 * S * DIM, a.Mt, As, Bs, mblk, nblk, tid, acc);
      tile_store(a.z, mblk, nblk, tid, acc);
    }
    grid.sync();
    // Phase D: score GEMM -> E, l
    const int njD = 256 * a.nb;
    for (int j = blockIdx.x; j < njD; j += nblocks) {
      const int lb = j % a.nb, t = j / a.nb;
      const int mblk = (t >> 4) * 128, nblk = (t & 15) * 128;
      f32x4 acc[4][4] = {};
      tile_kloop(a.z + (long)lb * S * DIM, a.xb + (long)(b0 + lb) * S * DIM,
                 As, Bs, mblk, nblk, tid, acc);
      score_epilogue(a.betas, l, a.E + (long)lb * S * S, b0 + lb, mblk, nblk,
                     tid, acc);
    }
    grid.sync();
    // Phase E1: c += E/l reduction (128*nb jobs)
    const int njE = 128 * a.nb;
    for (int j = blockIdx.x; j < njE; j += nblocks) {
      const int lb = j % a.nb, qs = j / a.nb;
      do_reduce_job(a.E + (long)lb * S * S, l + (b0 + lb) * S,
                    c + (b0 + lb) * S, qs * 16, tid);
    }
    grid.sync();
  }

  // Phase E2: y = c^T x (384 jobs)
  for (int j = blockIdx.x; j < 384; j += nblocks) {
    const int b = j / 48, rest = j % 48;
    do_y_job(a.xb, c, y, b, rest / 3, rest % 3, tid);
  }
  grid.sync();

  // Phase F: out = y Wv^T + bv (1536 jobs x 4 waves)
  for (int j = blockIdx.x; j < 1536; j += nblocks) {
    do_out_job(y, a.Wv_raw, a.bv_raw, a.out, j * 4 + (tid >> 6), f, tid);
  }
}

// ===================== fallback multi-kernel path ========================
__global__ __launch_bounds__(256) void detect_dtype(const unsigned short* __restrict__ x,
                                                    int* __restrict__ flag) {
  int bad = 0;
  for (int i = threadIdx.x; i < 2048; i += 256) {
    int e = (x[i] >> 7) & 0xFF;
    if (e < 0x60 || e >= 0x9F) bad = 1;
  }
  if (bad) atomicOr(flag, 1);
}

__global__ __launch_bounds__(256) void prep_kernel(const void* Wq_raw,
                                                   const void* Wk_raw,
                                                   const void* bq_raw,
                                                   short* T0, short* T1,
                                                   float* bvec,
                                                   const int* flag) {
  __shared__ __align__(16) char smem[17664];
  const int f = *flag;
  const int bx = blockIdx.x;
  if (bx < 288)
    do_transpose_job(bx < 144 ? Wq_raw : Wk_raw, bx < 144 ? T0 : T1, bx % 144,
                     f, threadIdx.x, smem);
  else
    do_bvec_job(Wk_raw, bq_raw, bvec, bx - 288, f, threadIdx.x,
                (float*)(smem + 16384));
}

__global__ __launch_bounds__(256) void mt_convert(const short* WkT,
                                                  const short* WqT, short* Mt,
                                                  const void* x_raw,
                                                  const int* mask,
                                                  const float* bvec, short* xb,
                                                  float* betas, float* lcy,
                                                  const int* flag) {
  __shared__ __align__(16) char smem[16384];
  const int bx = blockIdx.x;
  if (bx < 36) {
    f32x4 acc[4][4] = {};
    tile_kloop(WkT, WqT, (short*)smem, (short*)(smem + 8192), (bx / 6) * 128,
               (bx % 6) * 128, threadIdx.x, acc);
    tile_store(Mt, (bx / 6) * 128, (bx % 6) * 128, threadIdx.x, acc);
  } else if (bx < 4132) {
    const int n = (bx - 36) * 4 + (threadIdx.x >> 6);
    do_convert_job(x_raw, mask, bvec, xb, betas, n, *flag, threadIdx.x);
  } else {
    const int base = (bx - 4132) * 4096;
    for (int i = threadIdx.x; i < 4096; i += 256) {
      const int idx = base + i;
      if (idx < 38912) lcy[idx] = 0.f;
    }
  }
}

__global__ __launch_bounds__(256) void gemm_nt_tiled(const short* A,
                                                     const short* B, short* D) {
  __shared__ __align__(16) char smem[16384];
  f32x4 acc[4][4] = {};
  tile_kloop(A, B, (short*)smem, (short*)(smem + 8192), blockIdx.x * 128,
             blockIdx.y * 128, threadIdx.x, acc);
  tile_store(D, blockIdx.x * 128, blockIdx.y * 128, threadIdx.x, acc);
}

__global__ __launch_bounds__(256) void gemm_score(const short* z, const short* x,
                                                  const float* betas, float* l,
                                                  short* E, int b0) {
  __shared__ __align__(16) char smem[16384];
  const int lb = blockIdx.z, b = b0 + lb;
  f32x4 acc[4][4] = {};
  tile_kloop(z + (long)lb * S * DIM, x + (long)b * S * DIM, (short*)smem,
             (short*)(smem + 8192), blockIdx.x * 128, blockIdx.y * 128,
             threadIdx.x, acc);
  score_epilogue(betas, l, E + (long)lb * S * S, b, blockIdx.x * 128,
                 blockIdx.y * 128, threadIdx.x, acc);
}

__global__ __launch_bounds__(256) void reduce_c(const short* E, const float* l,
                                                float* c, int b0, int nb) {
  const int lb = blockIdx.y, b = b0 + lb;
  do_reduce_job(E + (long)lb * S * S, l + b * S, c + b * S, blockIdx.x * 16,
                threadIdx.x);
}

__global__ __launch_bounds__(256) void y_kernel(const short* xb, const float* c,
                                                float* y) {
  do_y_job(xb, c, y, blockIdx.z, blockIdx.y, blockIdx.x, threadIdx.x);
}

__global__ __launch_bounds__(256) void out_kernel(const float* y,
                                                  const void* Wv_raw,
                                                  const void* bv_raw, void* out,
                                                  const int* flag) {
  do_out_job(y, Wv_raw, bv_raw, out, blockIdx.x * 4 + (threadIdx.x >> 6),
             *flag, threadIdx.x);
}

extern "C" void kernel_launch(void* const* d_in, const int* in_sizes, int n_in,
                              void* d_out, int out_size, void* d_ws, size_t ws_size,
                              hipStream_t stream) {
  const void* x_raw = d_in[0];
  const int* mask = (const int*)d_in[1];
  const void* Wq_raw = d_in[2];
  const void* bq_raw = d_in[3];
  const void* Wk_raw = d_in[4];
  // d_in[5] = bk: provably cancels out of the computation.
  const void* Wv_raw = d_in[6];
  const void* bv_raw = d_in[7];

  char* ws = (char*)d_ws;
  short* xb = (short*)(ws);                 //          0 .. 25,165,824
  short* WqT = (short*)(ws + 25165824);     // 1,179,648 B
  short* WkT = (short*)(ws + 26345472);     // 1,179,648 B
  short* Mt = (short*)(ws + 27525120);      // 1,179,648 B  Mt[j,i]=M[i,j]
  float* betas = (float*)(ws + 28704768);   //    65,536 B
  float* bvec = (float*)(ws + 28770304);    //     3,072 B
  float* lcy = (float*)(ws + 28773376);     //   155,648 B (l,c,y contiguous)
  int* flag = (int*)(ws + 28929024);        //        64 B (fallback only)
  short* z = (short*)(ws + 28929088);       // nb * 3,145,728 B

  const size_t fixed = 28929088;
  const size_t zb = 3145728, eb = 8388608;
  int nb = 1;
  if (ws_size >= fixed + 8 * (zb + eb)) nb = 8;
  else if (ws_size >= fixed + 4 * (zb + eb)) nb = 4;
  else if (ws_size >= fixed + 2 * (zb + eb)) nb = 2;
  short* E = (short*)(ws + fixed + (size_t)nb * zb);
  const int rounds = BATCH / nb;

  MegaArgs a;
  a.x_raw = x_raw; a.mask = mask;
  a.Wq_raw = Wq_raw; a.bq_raw = bq_raw; a.Wk_raw = Wk_raw;
  a.Wv_raw = Wv_raw; a.bv_raw = bv_raw;
  a.out = d_out;
  a.xb = xb; a.WqT = WqT; a.WkT = WkT; a.Mt = Mt;
  a.betas = betas; a.bvec = bvec; a.lcy = lcy;
  a.z = z; a.E = E;
  a.nb = nb; a.rounds = rounds;

  int perCU = 0;
  hipError_t oe = hipOccupancyMaxActiveBlocksPerMultiprocessor(&perCU, mega, 256, 0);
  int grid = (oe == hipSuccess && perCU > 0) ? perCU * 256 : 1024;
  if (grid > 2048) grid = 2048;

  void* kargs[] = {(void*)&a};
  hipError_t err = hipLaunchCooperativeKernel((const void*)mega, dim3(grid),
                                              dim3(256), kargs, 0, stream);
  if (err == hipSuccess) return;

  // -------- fallback: round-7 multi-kernel path --------
  (void)hipMemsetAsync(lcy, 0, 155648, stream);
  (void)hipMemsetAsync(flag, 0, 64, stream);
  detect_dtype<<<1, 256, 0, stream>>>((const unsigned short*)x_raw, flag);
  prep_kernel<<<294, 256, 0, stream>>>(Wq_raw, Wk_raw, bq_raw, WqT, WkT, bvec, flag);
  mt_convert<<<4142, 256, 0, stream>>>(WkT, WqT, Mt, x_raw, mask, bvec, xb,
                                       betas, lcy, flag);
  float* l = lcy;
  float* c = lcy + 16384;
  float* y = lcy + 32768;
  for (int r = 0; r < rounds; ++r) {
    const int b0 = r * nb;
    gemm_nt_tiled<<<dim3(nb * 16, 6), 256, 0, stream>>>(
        xb + (long)b0 * S * DIM, Mt, z);
    gemm_score<<<dim3(16, 16, nb), 256, 0, stream>>>(z, xb, betas, l, E, b0);
    reduce_c<<<dim3(128, nb), 256, 0, stream>>>(E, l, c, b0, nb);
  }
  y_kernel<<<dim3(3, 16, 8), 256, 0, stream>>>(xb, c, y);
  out_kernel<<<1536, 256, 0, stream>>>(y, Wv_raw, bv_raw, d_out, flag);
}

// Round 9
// 753.477 us; speedup vs baseline: 1.1036x; 1.1036x over previous
//
#include <hip/hip_runtime.h>
#include <hip/hip_bf16.h>
#include <hip/hip_cooperative_groups.h>

namespace cg = cooperative_groups;

// AttentionPoolingAdvance: B=8,S=2048,D=768 (fp32 in/out, detected on device).
// out[b] = mean_q softmax((Q K^T)/sqrt(D), key-mask) V
// Algebra: out = (c^T x) Wv^T + bv with c_k=(1/S) sum_q w[q,k];
// score[q,k] == (z_q.x_k)/sqrt(D) + beta_k modulo softmax-invariant terms,
// z = x @ (Wq^T Wk), beta_k = x_k.(Wk^T bq)/sqrt(D); bk cancels.
// Round 9: mega kernel kept; launch_bounds (256,4)->(256,2). Round 8's ",4"
// capped unified regs at 128/lane; acc[4][4]=64 AGPRs left 64 VGPRs -> K-loop
// spilled to scratch (WRITE_SIZE 237 MB, MfmaUtil 2.5%). (256,2) restores the
// standalone gemm_score allocation (76 VGPR + 64 AGPR, no spill).

#define S 2048
#define DIM 768
#define BATCH 8

typedef __hip_bfloat16 bf16;
typedef __attribute__((ext_vector_type(8))) short bf16x8;
typedef __attribute__((ext_vector_type(4))) short short4v;
typedef __attribute__((ext_vector_type(4))) float f32x4;

__device__ __forceinline__ f32x4 mfma16(bf16x8 a, bf16x8 b, f32x4 c) {
  return __builtin_amdgcn_mfma_f32_16x16x32_bf16(a, b, c, 0, 0, 0);
}

__device__ __forceinline__ void load_lds16(const short* g, short* l) {
  __builtin_amdgcn_global_load_lds(
      (const __attribute__((address_space(1))) unsigned int*)g,
      (__attribute__((address_space(3))) unsigned int*)l, 16, 0, 0);
}

__device__ __forceinline__ float b2f(short u) {
  union { float f; unsigned u; } v;
  v.u = ((unsigned)(unsigned short)u) << 16;
  return v.f;
}

__device__ __forceinline__ short f2b(float f) {
  bf16 h = __float2bfloat16(f);
  return *(short*)&h;
}

#define INV_SCALE 0.03608439182435161f  // 1/sqrt(768)

// ---------------- shared tile-GEMM core (m97-style, 128x128, BK=32) --------
__device__ __forceinline__ void tile_kloop(const short* __restrict__ Abase,
                                           const short* __restrict__ Bbase,
                                           short* As, short* Bs, int mblk,
                                           int nblk, int tid,
                                           f32x4 (&acc)[4][4]) {
  const int lane = tid & 63;
  const int lr = lane & 15, quad = lane >> 4;
  const int wave = tid >> 6;
  const int wm = (wave >> 1) * 64, wn = (wave & 1) * 64;
  const int c0row = tid >> 2, colw = (tid & 3) * 8;
  const short* Ag0 = Abase + (long)(mblk + c0row) * DIM + colw;
  const short* Ag1 = Abase + (long)(mblk + 64 + c0row) * DIM + colw;
  const short* Bg0 = Bbase + (long)(nblk + c0row) * DIM + colw;
  const short* Bg1 = Bbase + (long)(nblk + 64 + c0row) * DIM + colw;
  short* Al0 = As + tid * 8;
  short* Al1 = As + 2048 + tid * 8;
  short* Bl0 = Bs + tid * 8;
  short* Bl1 = Bs + 2048 + tid * 8;
  for (int k0 = 0; k0 < DIM; k0 += 32) {
    load_lds16(Ag0 + k0, Al0);
    load_lds16(Ag1 + k0, Al1);
    load_lds16(Bg0 + k0, Bl0);
    load_lds16(Bg1 + k0, Bl1);
    asm volatile("s_waitcnt vmcnt(0)" ::: "memory");
    __syncthreads();
    bf16x8 af[4], bfr[4];
#pragma unroll
    for (int it = 0; it < 4; ++it)
      af[it] = *(const bf16x8*)(As + (wm + it * 16 + lr) * 32 + quad * 8);
#pragma unroll
    for (int jt = 0; jt < 4; ++jt)
      bfr[jt] = *(const bf16x8*)(Bs + (wn + jt * 16 + lr) * 32 + quad * 8);
#pragma unroll
    for (int it = 0; it < 4; ++it)
#pragma unroll
      for (int jt = 0; jt < 4; ++jt)
        acc[it][jt] = mfma16(af[it], bfr[jt], acc[it][jt]);
    __syncthreads();
  }
}

__device__ __forceinline__ void tile_store(short* __restrict__ D, int mblk,
                                           int nblk, int tid,
                                           f32x4 (&acc)[4][4]) {
  const int lane = tid & 63, lr = lane & 15, quad = lane >> 4;
  const int wave = tid >> 6, wm = (wave >> 1) * 64, wn = (wave & 1) * 64;
#pragma unroll
  for (int it = 0; it < 4; ++it)
#pragma unroll
    for (int jt = 0; jt < 4; ++jt)
#pragma unroll
      for (int r = 0; r < 4; ++r)
        D[(long)(mblk + wm + it * 16 + quad * 4 + r) * DIM + nblk + wn +
          jt * 16 + lr] = f2b(acc[it][jt][r]);
}

// -------- device sub-routines shared by mega kernel and fallback ----------
__device__ __forceinline__ void do_transpose_job(const void* src, short* dstT,
                                                 int r, int f, int tid,
                                                 char* smem) {
  unsigned short(*tile)[66] = (unsigned short(*)[66])smem;
  unsigned short* dst = (unsigned short*)dstT;
  const int obase = (r / 12) * 64, ibase = (r % 12) * 64;
  const int col = tid & 63, rq = tid >> 6;
#pragma unroll
  for (int rr = 0; rr < 64; rr += 4) {
    const long idx = (long)(obase + rr + rq) * DIM + ibase + col;
    const float v = f ? ((const float*)src)[idx] : b2f(((const short*)src)[idx]);
    tile[rr + rq][col] = (unsigned short)f2b(v);
  }
  __syncthreads();
#pragma unroll
  for (int rr = 0; rr < 64; rr += 4)
    dst[(long)(ibase + rr + rq) * DIM + obase + col] = tile[col][rr + rq];
  __syncthreads();
}

__device__ __forceinline__ void do_bvec_job(const void* Wk_raw,
                                            const void* bq_raw,
                                            float* __restrict__ bvec, int slice,
                                            int f, int tid, float* red) {
  const int jj = slice * 128 + (tid & 127);
  const int half = tid >> 7;
  float s = 0.f;
  if (f) {
    const float* W = (const float*)Wk_raw;
    const float* bq = (const float*)bq_raw;
    for (int o = half; o < DIM; o += 2) s += W[(long)o * DIM + jj] * bq[o];
  } else {
    const short* W = (const short*)Wk_raw;
    const short* bq = (const short*)bq_raw;
    for (int o = half; o < DIM; o += 2) s += b2f(W[(long)o * DIM + jj]) * b2f(bq[o]);
  }
  red[tid] = s;
  __syncthreads();
  if (tid < 128) bvec[jj] = red[tid] + red[tid + 128];
  __syncthreads();
}

__device__ __forceinline__ void do_convert_job(const void* x_raw,
                                               const int* mask,
                                               const float* bvec, short* xb,
                                               float* betas, int n, int f,
                                               int tid) {
  const int lane = tid & 63;
  short* xo = xb + (long)n * DIM;
  float s = 0.f;
  if (f) {
    const float4* x4 = (const float4*)((const float*)x_raw + (long)n * DIM);
    const float4* bv4 = (const float4*)bvec;
#pragma unroll
    for (int it = 0; it < 3; ++it) {
      const int idx = it * 64 + lane;
      const float4 v = x4[idx];
      const float4 bb = bv4[idx];
      short4v sv = {f2b(v.x), f2b(v.y), f2b(v.z), f2b(v.w)};
      *(short4v*)(xo + idx * 4) = sv;
      s += v.x * bb.x + v.y * bb.y + v.z * bb.z + v.w * bb.w;
    }
  } else {
    const short4v* x4 = (const short4v*)((const short*)x_raw + (long)n * DIM);
    const float4* bv4 = (const float4*)bvec;
#pragma unroll
    for (int it = 0; it < 3; ++it) {
      const int idx = it * 64 + lane;
      const short4v v = x4[idx];
      const float4 bb = bv4[idx];
      *(short4v*)(xo + idx * 4) = v;
      s += b2f(v.x) * bb.x + b2f(v.y) * bb.y + b2f(v.z) * bb.z + b2f(v.w) * bb.w;
    }
  }
#pragma unroll
  for (int off = 1; off < 64; off <<= 1) s += __shfl_xor(s, off, 64);
  if (lane == 0) betas[n] = mask[n] ? s * INV_SCALE : -1e30f;
}

__device__ __forceinline__ void score_epilogue(const float* betas, float* l_out,
                                               short* Eb, int b, int mblk,
                                               int nblk, int tid,
                                               f32x4 (&acc)[4][4]) {
  const int lane = tid & 63, lr = lane & 15, quad = lane >> 4;
  const int wave = tid >> 6, wm = (wave >> 1) * 64, wn = (wave & 1) * 64;
  float bet[4];
#pragma unroll
  for (int jt = 0; jt < 4; ++jt)
    bet[jt] = betas[b * S + nblk + wn + jt * 16 + lr];
  float* lrow = l_out + b * S;
#pragma unroll
  for (int it = 0; it < 4; ++it) {
#pragma unroll
    for (int r = 0; r < 4; ++r) {
      const int q = mblk + wm + it * 16 + quad * 4 + r;
      float s = 0.f;
#pragma unroll
      for (int jt = 0; jt < 4; ++jt) {
        float e = __expf(fminf(acc[it][jt][r] * INV_SCALE + bet[jt], 60.f));
        s += e;
        Eb[(long)q * S + nblk + wn + jt * 16 + lr] = f2b(e);
      }
      s += __shfl_xor(s, 1, 64);
      s += __shfl_xor(s, 2, 64);
      s += __shfl_xor(s, 4, 64);
      s += __shfl_xor(s, 8, 64);
      if (lr == 0) atomicAdd(&lrow[q], s);
    }
  }
}

__device__ __forceinline__ void do_reduce_job(const short* Eb, const float* lrow,
                                              float* crow, int q0, int tid) {
  const int k8 = tid * 8;
  float acc[8] = {};
#pragma unroll
  for (int q = q0; q < q0 + 16; ++q) {
    bf16x8 ev = *(const bf16x8*)(Eb + (long)q * S + k8);
    const float lv = lrow[q];
    const float rq = lv > 0.f ? 1.0f / lv : 0.f;
#pragma unroll
    for (int j = 0; j < 8; ++j) acc[j] += b2f(ev[j]) * rq;
  }
#pragma unroll
  for (int j = 0; j < 8; ++j)
    atomicAdd(&crow[k8 + j], acc[j] * (1.0f / 2048.0f));
}

__device__ __forceinline__ void do_y_job(const short* xb, const float* c,
                                         float* y, int b, int kc, int ic,
                                         int tid) {
  const int i = ic * 256 + tid;
  const int kstart = kc * 128;
  const short* xr = xb + (long)(b * S + kstart) * DIM + i;
  const float* cb = c + b * S + kstart;
  float acc = 0.f;
  for (int k = 0; k < 128; ++k) acc += cb[k] * b2f(xr[(long)k * DIM]);
  atomicAdd(&y[b * DIM + i], acc);
}

__device__ __forceinline__ void do_out_job(const float* y, const void* Wv_raw,
                                           const void* bv_raw, void* out, int w,
                                           int f, int tid) {
  const int lane = tid & 63;
  const int b = w / DIM, o = w % DIM;
  const float4* y4 = (const float4*)(y + (long)b * DIM);
  float s = 0.f;
  if (f) {
    const float4* wr = (const float4*)((const float*)Wv_raw + (long)o * DIM);
#pragma unroll
    for (int it = 0; it < 3; ++it) {
      const int idx = it * 64 + lane;
      const float4 a = y4[idx], wv = wr[idx];
      s += a.x * wv.x + a.y * wv.y + a.z * wv.z + a.w * wv.w;
    }
  } else {
    const short4v* wr = (const short4v*)((const short*)Wv_raw + (long)o * DIM);
#pragma unroll
    for (int it = 0; it < 3; ++it) {
      const int idx = it * 64 + lane;
      const float4 a = y4[idx];
      const short4v wv = wr[idx];
      s += a.x * b2f(wv.x) + a.y * b2f(wv.y) + a.z * b2f(wv.z) + a.w * b2f(wv.w);
    }
  }
#pragma unroll
  for (int off = 1; off < 64; off <<= 1) s += __shfl_xor(s, off, 64);
  if (lane == 0) {
    const float bias = f ? ((const float*)bv_raw)[o] : b2f(((const short*)bv_raw)[o]);
    const float v = s + bias;
    if (f) ((float*)out)[b * DIM + o] = v;
    else ((bf16*)out)[b * DIM + o] = __float2bfloat16(v);
  }
}

// ============================ mega kernel ================================
struct MegaArgs {
  const void* x_raw; const int* mask;
  const void* Wq_raw; const void* bq_raw; const void* Wk_raw;
  const void* Wv_raw; const void* bv_raw;
  void* out;
  short* xb; short* WqT; short* WkT; short* Mt;
  float* betas; float* bvec; float* lcy;  // l,c,y contiguous (38912 floats)
  short* z; short* E;
  int nb, rounds;
};

// (256,2): <=256 unified regs/lane -> 64 AGPR acc + ~110 VGPR, no spill.
__global__ __launch_bounds__(256, 2) void mega(MegaArgs a) {
  cg::grid_group grid = cg::this_grid();
  __shared__ __align__(16) char smem[17664];
  short* As = (short*)smem;
  short* Bs = (short*)(smem + 8192);
  float* red = (float*)(smem + 16384);
  const int tid = threadIdx.x;
  const int nblocks = gridDim.x;
  float* l = a.lcy;
  float* c = a.lcy + 16384;
  float* y = a.lcy + 32768;

  // per-block dtype detect (deterministic, no cross-block comm needed)
  int bad = 0;
  {
    const unsigned short* xs = (const unsigned short*)a.x_raw;
    for (int i = tid; i < 2048; i += 256) {
      int e = (xs[i] >> 7) & 0xFF;
      if (e < 0x60 || e >= 0x9F) bad = 1;
    }
    if (tid == 0) *(int*)(smem + 17408) = 0;
    __syncthreads();
    if (__any(bad) && (tid & 63) == 0) atomicOr((int*)(smem + 17408), 1);
    __syncthreads();
  }
  const int f = *(int*)(smem + 17408);
  __syncthreads();

  // Phase A: W transposes (288 jobs) + bvec slices (6 jobs)
  for (int j = blockIdx.x; j < 294; j += nblocks) {
    if (j < 288) {
      do_transpose_job(j < 144 ? a.Wq_raw : a.Wk_raw,
                       j < 144 ? a.WqT : a.WkT, j % 144, f, tid, smem);
    } else {
      do_bvec_job(a.Wk_raw, a.bq_raw, a.bvec, j - 288, f, tid, red);
    }
  }
  grid.sync();

  // Phase B: Mt GEMM (36) + x convert/beta (4096) + zero l/c/y (10)
  for (int j = blockIdx.x; j < 4142; j += nblocks) {
    if (j < 36) {
      f32x4 acc[4][4] = {};
      tile_kloop(a.WkT, a.WqT, As, Bs, (j / 6) * 128, (j % 6) * 128, tid, acc);
      tile_store(a.Mt, (j / 6) * 128, (j % 6) * 128, tid, acc);
    } else if (j < 4132) {
      const int n = (j - 36) * 4 + (tid >> 6);
      do_convert_job(a.x_raw, a.mask, a.bvec, a.xb, a.betas, n, f, tid);
    } else {
      const int base = (j - 4132) * 4096;
      for (int i = tid; i < 4096; i += 256) {
        const int idx = base + i;
        if (idx < 38912) a.lcy[idx] = 0.f;
      }
    }
  }
  grid.sync();

  for (int r = 0; r < a.rounds; ++r) {
    const int b0 = r * a.nb;
    // Phase C: z = x @ M  (nb*16 x 6 tiles)
    const int njC = a.nb * 96;
    for (int j = blockIdx.x; j < njC; j += nblocks) {
      const int mblk = (j / 6) * 128, nblk = (j % 6) * 128;
      f32x4 acc[4][4] = {};
      tile_kloop(a.xb + (long)b0 * S * DIM, a.Mt, As, Bs, mblk, nblk, tid, acc);
      tile_store(a.z, mblk, nblk, tid, acc);
    }
    grid.sync();
    // Phase D: score GEMM -> E, l
    const int njD = 256 * a.nb;
    for (int j = blockIdx.x; j < njD; j += nblocks) {
      const int lb = j % a.nb, t = j / a.nb;
      const int mblk = (t >> 4) * 128, nblk = (t & 15) * 128;
      f32x4 acc[4][4] = {};
      tile_kloop(a.z + (long)lb * S * DIM, a.xb + (long)(b0 + lb) * S * DIM,
                 As, Bs, mblk, nblk, tid, acc);
      score_epilogue(a.betas, l, a.E + (long)lb * S * S, b0 + lb, mblk, nblk,
                     tid, acc);
    }
    grid.sync();
    // Phase E1: c += E/l reduction (128*nb jobs)
    const int njE = 128 * a.nb;
    for (int j = blockIdx.x; j < njE; j += nblocks) {
      const int lb = j % a.nb, qs = j / a.nb;
      do_reduce_job(a.E + (long)lb * S * S, l + (b0 + lb) * S,
                    c + (b0 + lb) * S, qs * 16, tid);
    }
    grid.sync();
  }

  // Phase E2: y = c^T x (384 jobs)
  for (int j = blockIdx.x; j < 384; j += nblocks) {
    const int b = j / 48, rest = j % 48;
    do_y_job(a.xb, c, y, b, rest / 3, rest % 3, tid);
  }
  grid.sync();

  // Phase F: out = y Wv^T + bv (1536 jobs x 4 waves)
  for (int j = blockIdx.x; j < 1536; j += nblocks) {
    do_out_job(y, a.Wv_raw, a.bv_raw, a.out, j * 4 + (tid >> 6), f, tid);
  }
}

// ===================== fallback multi-kernel path ========================
__global__ __launch_bounds__(256) void detect_dtype(const unsigned short* __restrict__ x,
                                                    int* __restrict__ flag) {
  int bad = 0;
  for (int i = threadIdx.x; i < 2048; i += 256) {
    int e = (x[i] >> 7) & 0xFF;
    if (e < 0x60 || e >= 0x9F) bad = 1;
  }
  if (bad) atomicOr(flag, 1);
}

__global__ __launch_bounds__(256) void prep_kernel(const void* Wq_raw,
                                                   const void* Wk_raw,
                                                   const void* bq_raw,
                                                   short* T0, short* T1,
                                                   float* bvec,
                                                   const int* flag) {
  __shared__ __align__(16) char smem[17664];
  const int f = *flag;
  const int bx = blockIdx.x;
  if (bx < 288)
    do_transpose_job(bx < 144 ? Wq_raw : Wk_raw, bx < 144 ? T0 : T1, bx % 144,
                     f, threadIdx.x, smem);
  else
    do_bvec_job(Wk_raw, bq_raw, bvec, bx - 288, f, threadIdx.x,
                (float*)(smem + 16384));
}

__global__ __launch_bounds__(256) void mt_convert(const short* WkT,
                                                  const short* WqT, short* Mt,
                                                  const void* x_raw,
                                                  const int* mask,
                                                  const float* bvec, short* xb,
                                                  float* betas, float* lcy,
                                                  const int* flag) {
  __shared__ __align__(16) char smem[16384];
  const int bx = blockIdx.x;
  if (bx < 36) {
    f32x4 acc[4][4] = {};
    tile_kloop(WkT, WqT, (short*)smem, (short*)(smem + 8192), (bx / 6) * 128,
               (bx % 6) * 128, threadIdx.x, acc);
    tile_store(Mt, (bx / 6) * 128, (bx % 6) * 128, threadIdx.x, acc);
  } else if (bx < 4132) {
    const int n = (bx - 36) * 4 + (threadIdx.x >> 6);
    do_convert_job(x_raw, mask, bvec, xb, betas, n, *flag, threadIdx.x);
  } else {
    const int base = (bx - 4132) * 4096;
    for (int i = threadIdx.x; i < 4096; i += 256) {
      const int idx = base + i;
      if (idx < 38912) lcy[idx] = 0.f;
    }
  }
}

__global__ __launch_bounds__(256) void gemm_nt_tiled(const short* A,
                                                     const short* B, short* D) {
  __shared__ __align__(16) char smem[16384];
  f32x4 acc[4][4] = {};
  tile_kloop(A, B, (short*)smem, (short*)(smem + 8192), blockIdx.x * 128,
             blockIdx.y * 128, threadIdx.x, acc);
  tile_store(D, blockIdx.x * 128, blockIdx.y * 128, threadIdx.x, acc);
}

__global__ __launch_bounds__(256) void gemm_score(const short* z, const short* x,
                                                  const float* betas, float* l,
                                                  short* E, int b0) {
  __shared__ __align__(16) char smem[16384];
  const int lb = blockIdx.z, b = b0 + lb;
  f32x4 acc[4][4] = {};
  tile_kloop(z + (long)lb * S * DIM, x + (long)b * S * DIM, (short*)smem,
             (short*)(smem + 8192), blockIdx.x * 128, blockIdx.y * 128,
             threadIdx.x, acc);
  score_epilogue(betas, l, E + (long)lb * S * S, b, blockIdx.x * 128,
                 blockIdx.y * 128, threadIdx.x, acc);
}

__global__ __launch_bounds__(256) void reduce_c(const short* E, const float* l,
                                                float* c, int b0, int nb) {
  const int lb = blockIdx.y, b = b0 + lb;
  do_reduce_job(E + (long)lb * S * S, l + b * S, c + b * S, blockIdx.x * 16,
                threadIdx.x);
}

__global__ __launch_bounds__(256) void y_kernel(const short* xb, const float* c,
                                                float* y) {
  do_y_job(xb, c, y, blockIdx.z, blockIdx.y, blockIdx.x, threadIdx.x);
}

__global__ __launch_bounds__(256) void out_kernel(const float* y,
                                                  const void* Wv_raw,
                                                  const void* bv_raw, void* out,
                                                  const int* flag) {
  do_out_job(y, Wv_raw, bv_raw, out, blockIdx.x * 4 + (threadIdx.x >> 6),
             *flag, threadIdx.x);
}

extern "C" void kernel_launch(void* const* d_in, const int* in_sizes, int n_in,
                              void* d_out, int out_size, void* d_ws, size_t ws_size,
                              hipStream_t stream) {
  const void* x_raw = d_in[0];
  const int* mask = (const int*)d_in[1];
  const void* Wq_raw = d_in[2];
  const void* bq_raw = d_in[3];
  const void* Wk_raw = d_in[4];
  // d_in[5] = bk: provably cancels out of the computation.
  const void* Wv_raw = d_in[6];
  const void* bv_raw = d_in[7];

  char* ws = (char*)d_ws;
  short* xb = (short*)(ws);                 //          0 .. 25,165,824
  short* WqT = (short*)(ws + 25165824);     // 1,179,648 B
  short* WkT = (short*)(ws + 26345472);     // 1,179,648 B
  short* Mt = (short*)(ws + 27525120);      // 1,179,648 B  Mt[j,i]=M[i,j]
  float* betas = (float*)(ws + 28704768);   //    65,536 B
  float* bvec = (float*)(ws + 28770304);    //     3,072 B
  float* lcy = (float*)(ws + 28773376);     //   155,648 B (l,c,y contiguous)
  int* flag = (int*)(ws + 28929024);        //        64 B (fallback only)
  short* z = (short*)(ws + 28929088);       // nb * 3,145,728 B

  const size_t fixed = 28929088;
  const size_t zb = 3145728, eb = 8388608;
  int nb = 1;
  if (ws_size >= fixed + 8 * (zb + eb)) nb = 8;
  else if (ws_size >= fixed + 4 * (zb + eb)) nb = 4;
  else if (ws_size >= fixed + 2 * (zb + eb)) nb = 2;
  short* E = (short*)(ws + fixed + (size_t)nb * zb);
  const int rounds = BATCH / nb;

  MegaArgs a;
  a.x_raw = x_raw; a.mask = mask;
  a.Wq_raw = Wq_raw; a.bq_raw = bq_raw; a.Wk_raw = Wk_raw;
  a.Wv_raw = Wv_raw; a.bv_raw = bv_raw;
  a.out = d_out;
  a.xb = xb; a.WqT = WqT; a.WkT = WkT; a.Mt = Mt;
  a.betas = betas; a.bvec = bvec; a.lcy = lcy;
  a.z = z; a.E = E;
  a.nb = nb; a.rounds = rounds;

  int perCU = 0;
  hipError_t oe = hipOccupancyMaxActiveBlocksPerMultiprocessor(&perCU, mega, 256, 0);
  int grid = (oe == hipSuccess && perCU > 0) ? perCU * 256 : 512;
  if (grid > 2048) grid = 2048;

  void* kargs[] = {(void*)&a};
  hipError_t err = hipLaunchCooperativeKernel((const void*)mega, dim3(grid),
                                              dim3(256), kargs, 0, stream);
  if (err == hipSuccess) return;

  // -------- fallback: round-7 multi-kernel path --------
  (void)hipMemsetAsync(lcy, 0, 155648, stream);
  (void)hipMemsetAsync(flag, 0, 64, stream);
  detect_dtype<<<1, 256, 0, stream>>>((const unsigned short*)x_raw, flag);
  prep_kernel<<<294, 256, 0, stream>>>(Wq_raw, Wk_raw, bq_raw, WqT, WkT, bvec, flag);
  mt_convert<<<4142, 256, 0, stream>>>(WkT, WqT, Mt, x_raw, mask, bvec, xb,
                                       betas, lcy, flag);
  float* l = lcy;
  float* c = lcy + 16384;
  float* y = lcy + 32768;
  for (int r = 0; r < rounds; ++r) {
    const int b0 = r * nb;
    gemm_nt_tiled<<<dim3(nb * 16, 6), 256, 0, stream>>>(
        xb + (long)b0 * S * DIM, Mt, z);
    gemm_score<<<dim3(16, 16, nb), 256, 0, stream>>>(z, xb, betas, l, E, b0);
    reduce_c<<<dim3(128, nb), 256, 0, stream>>>(E, l, c, b0, nb);
  }
  y_kernel<<<dim3(3, 16, 8), 256, 0, stream>>>(xb, c, y);
  out_kernel<<<1536, 256, 0, stream>>>(y, Wv_raw, bv_raw, d_out, flag);
}

// Round 10
// 410.833 us; speedup vs baseline: 2.0240x; 1.8340x over previous
//
#include <hip/hip_runtime.h>
#include <hip/hip_bf16.h>

// AttentionPoolingAdvance: B=8,S=2048,D=768 (fp32 in/out, detected on device).
// out[b] = mean_q softmax((Q K^T)/sqrt(D), key-mask) V
// Algebra: out = (c^T x) Wv^T + bv with c_k=(1/S) sum_q w[q,k];
// score[q,k] == (z_q.x_k)/sqrt(D) + beta_k modulo softmax-invariant terms,
// z = x @ (Wq^T Wk), beta_k = x_k.(Wk^T bq)/sqrt(D); bk cancels.
// Round 10: mega/cooperative path abandoned (753us, residual spill + no
// per-phase visibility). Back to the proven multi-kernel path (331us),
// streamlined 10 -> 7 dispatches: no memsets (zeroing rides in mt_convert,
// bvec written non-atomic), no detect dispatch (prep detects dtype inline
// and publishes the flag).

#define S 2048
#define DIM 768
#define BATCH 8

typedef __hip_bfloat16 bf16;
typedef __attribute__((ext_vector_type(8))) short bf16x8;
typedef __attribute__((ext_vector_type(4))) short short4v;
typedef __attribute__((ext_vector_type(4))) float f32x4;

__device__ __forceinline__ f32x4 mfma16(bf16x8 a, bf16x8 b, f32x4 c) {
  return __builtin_amdgcn_mfma_f32_16x16x32_bf16(a, b, c, 0, 0, 0);
}

__device__ __forceinline__ void load_lds16(const short* g, short* l) {
  __builtin_amdgcn_global_load_lds(
      (const __attribute__((address_space(1))) unsigned int*)g,
      (__attribute__((address_space(3))) unsigned int*)l, 16, 0, 0);
}

__device__ __forceinline__ float b2f(short u) {
  union { float f; unsigned u; } v;
  v.u = ((unsigned)(unsigned short)u) << 16;
  return v.f;
}

__device__ __forceinline__ short f2b(float f) {
  bf16 h = __float2bfloat16(f);
  return *(short*)&h;
}

#define INV_SCALE 0.03608439182435161f  // 1/sqrt(768)

// ---------------- shared tile-GEMM core (m97-style, 128x128, BK=32) --------
__device__ __forceinline__ void tile_kloop(const short* __restrict__ Abase,
                                           const short* __restrict__ Bbase,
                                           short* As, short* Bs, int mblk,
                                           int nblk, int tid,
                                           f32x4 (&acc)[4][4]) {
  const int lane = tid & 63;
  const int lr = lane & 15, quad = lane >> 4;
  const int wave = tid >> 6;
  const int wm = (wave >> 1) * 64, wn = (wave & 1) * 64;
  const int c0row = tid >> 2, colw = (tid & 3) * 8;
  const short* Ag0 = Abase + (long)(mblk + c0row) * DIM + colw;
  const short* Ag1 = Abase + (long)(mblk + 64 + c0row) * DIM + colw;
  const short* Bg0 = Bbase + (long)(nblk + c0row) * DIM + colw;
  const short* Bg1 = Bbase + (long)(nblk + 64 + c0row) * DIM + colw;
  short* Al0 = As + tid * 8;
  short* Al1 = As + 2048 + tid * 8;
  short* Bl0 = Bs + tid * 8;
  short* Bl1 = Bs + 2048 + tid * 8;
  for (int k0 = 0; k0 < DIM; k0 += 32) {
    load_lds16(Ag0 + k0, Al0);
    load_lds16(Ag1 + k0, Al1);
    load_lds16(Bg0 + k0, Bl0);
    load_lds16(Bg1 + k0, Bl1);
    asm volatile("s_waitcnt vmcnt(0)" ::: "memory");
    __syncthreads();
    bf16x8 af[4], bfr[4];
#pragma unroll
    for (int it = 0; it < 4; ++it)
      af[it] = *(const bf16x8*)(As + (wm + it * 16 + lr) * 32 + quad * 8);
#pragma unroll
    for (int jt = 0; jt < 4; ++jt)
      bfr[jt] = *(const bf16x8*)(Bs + (wn + jt * 16 + lr) * 32 + quad * 8);
#pragma unroll
    for (int it = 0; it < 4; ++it)
#pragma unroll
      for (int jt = 0; jt < 4; ++jt)
        acc[it][jt] = mfma16(af[it], bfr[jt], acc[it][jt]);
    __syncthreads();
  }
}

__device__ __forceinline__ void tile_store(short* __restrict__ D, int mblk,
                                           int nblk, int tid,
                                           f32x4 (&acc)[4][4]) {
  const int lane = tid & 63, lr = lane & 15, quad = lane >> 4;
  const int wave = tid >> 6, wm = (wave >> 1) * 64, wn = (wave & 1) * 64;
#pragma unroll
  for (int it = 0; it < 4; ++it)
#pragma unroll
    for (int jt = 0; jt < 4; ++jt)
#pragma unroll
      for (int r = 0; r < 4; ++r)
        D[(long)(mblk + wm + it * 16 + quad * 4 + r) * DIM + nblk + wn +
          jt * 16 + lr] = f2b(acc[it][jt][r]);
}

// ----------------------- device sub-routines ------------------------------
__device__ __forceinline__ void do_transpose_job(const void* src, short* dstT,
                                                 int r, int f, int tid,
                                                 char* smem) {
  unsigned short(*tile)[66] = (unsigned short(*)[66])smem;
  unsigned short* dst = (unsigned short*)dstT;
  const int obase = (r / 12) * 64, ibase = (r % 12) * 64;
  const int col = tid & 63, rq = tid >> 6;
#pragma unroll
  for (int rr = 0; rr < 64; rr += 4) {
    const long idx = (long)(obase + rr + rq) * DIM + ibase + col;
    const float v = f ? ((const float*)src)[idx] : b2f(((const short*)src)[idx]);
    tile[rr + rq][col] = (unsigned short)f2b(v);
  }
  __syncthreads();
#pragma unroll
  for (int rr = 0; rr < 64; rr += 4)
    dst[(long)(ibase + rr + rq) * DIM + obase + col] = tile[col][rr + rq];
  __syncthreads();
}

__device__ __forceinline__ void do_bvec_job(const void* Wk_raw,
                                            const void* bq_raw,
                                            float* __restrict__ bvec, int slice,
                                            int f, int tid, float* red) {
  const int jj = slice * 128 + (tid & 127);
  const int half = tid >> 7;
  float s = 0.f;
  if (f) {
    const float* W = (const float*)Wk_raw;
    const float* bq = (const float*)bq_raw;
    for (int o = half; o < DIM; o += 2) s += W[(long)o * DIM + jj] * bq[o];
  } else {
    const short* W = (const short*)Wk_raw;
    const short* bq = (const short*)bq_raw;
    for (int o = half; o < DIM; o += 2) s += b2f(W[(long)o * DIM + jj]) * b2f(bq[o]);
  }
  red[tid] = s;
  __syncthreads();
  if (tid < 128) bvec[jj] = red[tid] + red[tid + 128];
  __syncthreads();
}

__device__ __forceinline__ void do_convert_job(const void* x_raw,
                                               const int* mask,
                                               const float* bvec, short* xb,
                                               float* betas, int n, int f,
                                               int tid) {
  const int lane = tid & 63;
  short* xo = xb + (long)n * DIM;
  float s = 0.f;
  if (f) {
    const float4* x4 = (const float4*)((const float*)x_raw + (long)n * DIM);
    const float4* bv4 = (const float4*)bvec;
#pragma unroll
    for (int it = 0; it < 3; ++it) {
      const int idx = it * 64 + lane;
      const float4 v = x4[idx];
      const float4 bb = bv4[idx];
      short4v sv = {f2b(v.x), f2b(v.y), f2b(v.z), f2b(v.w)};
      *(short4v*)(xo + idx * 4) = sv;
      s += v.x * bb.x + v.y * bb.y + v.z * bb.z + v.w * bb.w;
    }
  } else {
    const short4v* x4 = (const short4v*)((const short*)x_raw + (long)n * DIM);
    const float4* bv4 = (const float4*)bvec;
#pragma unroll
    for (int it = 0; it < 3; ++it) {
      const int idx = it * 64 + lane;
      const short4v v = x4[idx];
      const float4 bb = bv4[idx];
      *(short4v*)(xo + idx * 4) = v;
      s += b2f(v.x) * bb.x + b2f(v.y) * bb.y + b2f(v.z) * bb.z + b2f(v.w) * bb.w;
    }
  }
#pragma unroll
  for (int off = 1; off < 64; off <<= 1) s += __shfl_xor(s, off, 64);
  if (lane == 0) betas[n] = mask[n] ? s * INV_SCALE : -1e30f;
}

__device__ __forceinline__ void score_epilogue(const float* betas, float* l_out,
                                               short* Eb, int b, int mblk,
                                               int nblk, int tid,
                                               f32x4 (&acc)[4][4]) {
  const int lane = tid & 63, lr = lane & 15, quad = lane >> 4;
  const int wave = tid >> 6, wm = (wave >> 1) * 64, wn = (wave & 1) * 64;
  float bet[4];
#pragma unroll
  for (int jt = 0; jt < 4; ++jt)
    bet[jt] = betas[b * S + nblk + wn + jt * 16 + lr];
  float* lrow = l_out + b * S;
#pragma unroll
  for (int it = 0; it < 4; ++it) {
#pragma unroll
    for (int r = 0; r < 4; ++r) {
      const int q = mblk + wm + it * 16 + quad * 4 + r;
      float s = 0.f;
#pragma unroll
      for (int jt = 0; jt < 4; ++jt) {
        float e = __expf(fminf(acc[it][jt][r] * INV_SCALE + bet[jt], 60.f));
        s += e;
        Eb[(long)q * S + nblk + wn + jt * 16 + lr] = f2b(e);
      }
      s += __shfl_xor(s, 1, 64);
      s += __shfl_xor(s, 2, 64);
      s += __shfl_xor(s, 4, 64);
      s += __shfl_xor(s, 8, 64);
      if (lr == 0) atomicAdd(&lrow[q], s);
    }
  }
}

__device__ __forceinline__ void do_reduce_job(const short* Eb, const float* lrow,
                                              float* crow, int q0, int tid) {
  const int k8 = tid * 8;
  float acc[8] = {};
#pragma unroll
  for (int q = q0; q < q0 + 16; ++q) {
    bf16x8 ev = *(const bf16x8*)(Eb + (long)q * S + k8);
    const float lv = lrow[q];
    const float rq = lv > 0.f ? 1.0f / lv : 0.f;
#pragma unroll
    for (int j = 0; j < 8; ++j) acc[j] += b2f(ev[j]) * rq;
  }
#pragma unroll
  for (int j = 0; j < 8; ++j)
    atomicAdd(&crow[k8 + j], acc[j] * (1.0f / 2048.0f));
}

__device__ __forceinline__ void do_y_job(const short* xb, const float* c,
                                         float* y, int b, int kc, int ic,
                                         int tid) {
  const int i = ic * 256 + tid;
  const int kstart = kc * 128;
  const short* xr = xb + (long)(b * S + kstart) * DIM + i;
  const float* cb = c + b * S + kstart;
  float acc = 0.f;
  for (int k = 0; k < 128; ++k) acc += cb[k] * b2f(xr[(long)k * DIM]);
  atomicAdd(&y[b * DIM + i], acc);
}

__device__ __forceinline__ void do_out_job(const float* y, const void* Wv_raw,
                                           const void* bv_raw, void* out, int w,
                                           int f, int tid) {
  const int lane = tid & 63;
  const int b = w / DIM, o = w % DIM;
  const float4* y4 = (const float4*)(y + (long)b * DIM);
  float s = 0.f;
  if (f) {
    const float4* wr = (const float4*)((const float*)Wv_raw + (long)o * DIM);
#pragma unroll
    for (int it = 0; it < 3; ++it) {
      const int idx = it * 64 + lane;
      const float4 a = y4[idx], wv = wr[idx];
      s += a.x * wv.x + a.y * wv.y + a.z * wv.z + a.w * wv.w;
    }
  } else {
    const short4v* wr = (const short4v*)((const short*)Wv_raw + (long)o * DIM);
#pragma unroll
    for (int it = 0; it < 3; ++it) {
      const int idx = it * 64 + lane;
      const float4 a = y4[idx];
      const short4v wv = wr[idx];
      s += a.x * b2f(wv.x) + a.y * b2f(wv.y) + a.z * b2f(wv.z) + a.w * b2f(wv.w);
    }
  }
#pragma unroll
  for (int off = 1; off < 64; off <<= 1) s += __shfl_xor(s, off, 64);
  if (lane == 0) {
    const float bias = f ? ((const float*)bv_raw)[o] : b2f(((const short*)bv_raw)[o]);
    const float v = s + bias;
    if (f) ((float*)out)[b * DIM + o] = v;
    else ((bf16*)out)[b * DIM + o] = __float2bfloat16(v);
  }
}

// ============================== kernels ===================================
// prep: detects dtype inline (publishes flag), transposes Wq/Wk (288 jobs),
// bvec slices (6 jobs). grid 294.
__global__ __launch_bounds__(256) void prep_kernel(const void* Wq_raw,
                                                   const void* Wk_raw,
                                                   const void* bq_raw,
                                                   const void* x_raw,
                                                   short* T0, short* T1,
                                                   float* bvec,
                                                   int* flag_out) {
  __shared__ __align__(16) char smem[17664];
  int* sflag = (int*)(smem + 17600);
  const unsigned short* xs = (const unsigned short*)x_raw;
  if (threadIdx.x == 0) *sflag = 0;
  __syncthreads();
  int bad = 0;
  for (int i = threadIdx.x; i < 2048; i += 256) {
    int e = (xs[i] >> 7) & 0xFF;
    if (e < 0x60 || e >= 0x9F) bad = 1;
  }
  if (__any(bad) && (threadIdx.x & 63) == 0) atomicOr(sflag, 1);
  __syncthreads();
  const int f = *sflag;
  __syncthreads();
  if (blockIdx.x == 0 && threadIdx.x == 0) *flag_out = f;

  const int bx = blockIdx.x;
  if (bx < 288)
    do_transpose_job(bx < 144 ? Wq_raw : Wk_raw, bx < 144 ? T0 : T1, bx % 144,
                     f, threadIdx.x, smem);
  else
    do_bvec_job(Wk_raw, bq_raw, bvec, bx - 288, f, threadIdx.x,
                (float*)(smem + 16384));
}

// mt_convert: Mt GEMM (36) + x convert/beta (4096) + zero l/c/y (10). 4142.
__global__ __launch_bounds__(256) void mt_convert(const short* WkT,
                                                  const short* WqT, short* Mt,
                                                  const void* x_raw,
                                                  const int* mask,
                                                  const float* bvec, short* xb,
                                                  float* betas, float* lcy,
                                                  const int* flag) {
  __shared__ __align__(16) char smem[16384];
  const int bx = blockIdx.x;
  if (bx < 36) {
    f32x4 acc[4][4] = {};
    tile_kloop(WkT, WqT, (short*)smem, (short*)(smem + 8192), (bx / 6) * 128,
               (bx % 6) * 128, threadIdx.x, acc);
    tile_store(Mt, (bx / 6) * 128, (bx % 6) * 128, threadIdx.x, acc);
  } else if (bx < 4132) {
    const int n = (bx - 36) * 4 + (threadIdx.x >> 6);
    do_convert_job(x_raw, mask, bvec, xb, betas, n, *flag, threadIdx.x);
  } else {
    const int base = (bx - 4132) * 4096;
    for (int i = threadIdx.x; i < 4096; i += 256) {
      const int idx = base + i;
      if (idx < 38912) lcy[idx] = 0.f;
    }
  }
}

__global__ __launch_bounds__(256) void gemm_nt_tiled(const short* A,
                                                     const short* B, short* D) {
  __shared__ __align__(16) char smem[16384];
  f32x4 acc[4][4] = {};
  tile_kloop(A, B, (short*)smem, (short*)(smem + 8192), blockIdx.x * 128,
             blockIdx.y * 128, threadIdx.x, acc);
  tile_store(D, blockIdx.x * 128, blockIdx.y * 128, threadIdx.x, acc);
}

__global__ __launch_bounds__(256) void gemm_score(const short* z, const short* x,
                                                  const float* betas, float* l,
                                                  short* E, int b0) {
  __shared__ __align__(16) char smem[16384];
  const int lb = blockIdx.z, b = b0 + lb;
  f32x4 acc[4][4] = {};
  tile_kloop(z + (long)lb * S * DIM, x + (long)b * S * DIM, (short*)smem,
             (short*)(smem + 8192), blockIdx.x * 128, blockIdx.y * 128,
             threadIdx.x, acc);
  score_epilogue(betas, l, E + (long)lb * S * S, b, blockIdx.x * 128,
                 blockIdx.y * 128, threadIdx.x, acc);
}

__global__ __launch_bounds__(256) void reduce_c(const short* E, const float* l,
                                                float* c, int b0) {
  const int lb = blockIdx.y, b = b0 + lb;
  do_reduce_job(E + (long)lb * S * S, l + b * S, c + b * S, blockIdx.x * 16,
                threadIdx.x);
}

__global__ __launch_bounds__(256) void y_kernel(const short* xb, const float* c,
                                                float* y) {
  do_y_job(xb, c, y, blockIdx.z, blockIdx.y, blockIdx.x, threadIdx.x);
}

__global__ __launch_bounds__(256) void out_kernel(const float* y,
                                                  const void* Wv_raw,
                                                  const void* bv_raw, void* out,
                                                  const int* flag) {
  do_out_job(y, Wv_raw, bv_raw, out, blockIdx.x * 4 + (threadIdx.x >> 6),
             *flag, threadIdx.x);
}

extern "C" void kernel_launch(void* const* d_in, const int* in_sizes, int n_in,
                              void* d_out, int out_size, void* d_ws, size_t ws_size,
                              hipStream_t stream) {
  const void* x_raw = d_in[0];
  const int* mask = (const int*)d_in[1];
  const void* Wq_raw = d_in[2];
  const void* bq_raw = d_in[3];
  const void* Wk_raw = d_in[4];
  // d_in[5] = bk: provably cancels out of the computation.
  const void* Wv_raw = d_in[6];
  const void* bv_raw = d_in[7];

  char* ws = (char*)d_ws;
  short* xb = (short*)(ws);                 //          0 .. 25,165,824
  short* WqT = (short*)(ws + 25165824);     // 1,179,648 B
  short* WkT = (short*)(ws + 26345472);     // 1,179,648 B
  short* Mt = (short*)(ws + 27525120);      // 1,179,648 B  Mt[j,i]=M[i,j]
  float* betas = (float*)(ws + 28704768);   //    65,536 B
  float* bvec = (float*)(ws + 28770304);    //     3,072 B
  float* lcy = (float*)(ws + 28773376);     //   155,648 B (l,c,y contiguous)
  int* flag = (int*)(ws + 28929024);        //        64 B
  short* z = (short*)(ws + 28929088);       // nb * 3,145,728 B

  const size_t fixed = 28929088;
  const size_t zb = 3145728, eb = 8388608;
  int nb = 1;
  if (ws_size >= fixed + 8 * (zb + eb)) nb = 8;
  else if (ws_size >= fixed + 4 * (zb + eb)) nb = 4;
  else if (ws_size >= fixed + 2 * (zb + eb)) nb = 2;
  short* E = (short*)(ws + fixed + (size_t)nb * zb);
  const int rounds = BATCH / nb;

  float* l = lcy;
  float* c = lcy + 16384;
  float* y = lcy + 32768;

  prep_kernel<<<294, 256, 0, stream>>>(Wq_raw, Wk_raw, bq_raw, x_raw, WqT, WkT,
                                       bvec, flag);
  mt_convert<<<4142, 256, 0, stream>>>(WkT, WqT, Mt, x_raw, mask, bvec, xb,
                                       betas, lcy, flag);
  for (int r = 0; r < rounds; ++r) {
    const int b0 = r * nb;
    gemm_nt_tiled<<<dim3(nb * 16, 6), 256, 0, stream>>>(
        xb + (long)b0 * S * DIM, Mt, z);
    gemm_score<<<dim3(16, 16, nb), 256, 0, stream>>>(z, xb, betas, l, E, b0);
    reduce_c<<<dim3(128, nb), 256, 0, stream>>>(E, l, c, b0);
  }
  y_kernel<<<dim3(3, 16, 8), 256, 0, stream>>>(xb, c, y);
  out_kernel<<<1536, 256, 0, stream>>>(y, Wv_raw, bv_raw, d_out, flag);
}

// Round 12
// 400.897 us; speedup vs baseline: 2.0741x; 1.0248x over previous
//
#include <hip/hip_runtime.h>
#include <hip/hip_bf16.h>

// AttentionPoolingAdvance: B=8,S=2048,D=768 (fp32 in/out, detected on device).
// out[b] = mean_q softmax((Q K^T)/sqrt(D), key-mask) V
// Algebra: out = (c^T x) Wv^T + bv with c_k=(1/S) sum_q w[q,k];
// score[q,k] == (z_q.x_k)/sqrt(D) + beta_k modulo softmax-invariant terms,
// z = x @ (Wq^T Wk), beta_k = x_k.(Wk^T bq)/sqrt(D); bk cancels.
// Round 12 = round 11 with the NT-load compile fix (ext_vector f32x4 instead
// of HIP float4 class): BK=64 K-loop (12 iters, half the barrier drains),
// XOR bank-swizzle on LDS staging (kills 8-way ds_read_b128 conflicts),
// non-temporal E stores/loads + x_raw loads. 7 dispatches.

#define S 2048
#define DIM 768
#define BATCH 8

typedef __hip_bfloat16 bf16;
typedef __attribute__((ext_vector_type(8))) short bf16x8;
typedef __attribute__((ext_vector_type(4))) short short4v;
typedef __attribute__((ext_vector_type(4))) float f32x4;

__device__ __forceinline__ f32x4 mfma16(bf16x8 a, bf16x8 b, f32x4 c) {
  return __builtin_amdgcn_mfma_f32_16x16x32_bf16(a, b, c, 0, 0, 0);
}

__device__ __forceinline__ void load_lds16(const short* g, short* l) {
  __builtin_amdgcn_global_load_lds(
      (const __attribute__((address_space(1))) unsigned int*)g,
      (__attribute__((address_space(3))) unsigned int*)l, 16, 0, 0);
}

__device__ __forceinline__ float b2f(short u) {
  union { float f; unsigned u; } v;
  v.u = ((unsigned)(unsigned short)u) << 16;
  return v.f;
}

__device__ __forceinline__ short f2b(float f) {
  bf16 h = __float2bfloat16(f);
  return *(short*)&h;
}

#define INV_SCALE 0.03608439182435161f  // 1/sqrt(768)

// ---------------- tile-GEMM core: 128x128 C-tile, BK=64, K=768 ------------
// LDS layout per matrix: 128 rows x 64 shorts (16 KB), column-group XOR
// swizzle: LDS[row][g] = global[row][g ^ (row&7)] (g = 8-short group).
// Staging: op j, lane t -> row j*32 + t/8, global col ((t ^ (t>>3))&7)*8;
// LDS dest = base + j*4KB + t*16B (contiguous, as global_load_lds requires).
// Reader XORs group with lr&7 -> 16 lanes spread over all 32 banks (2-way).
__device__ __forceinline__ void tile_kloop(const short* __restrict__ Abase,
                                           const short* __restrict__ Bbase,
                                           short* As, short* Bs, int mblk,
                                           int nblk, int tid,
                                           f32x4 (&acc)[4][4]) {
  const int lane = tid & 63;
  const int lr = lane & 15, quad = lane >> 4;
  const int wave = tid >> 6;
  const int wm = (wave >> 1) * 64, wn = (wave & 1) * 64;
  const int srow = tid >> 3;                 // 0..31
  const int scol = ((tid ^ (tid >> 3)) & 7) * 8;
  const short* Ag = Abase + (long)(mblk + srow) * DIM + scol;
  const short* Bg = Bbase + (long)(nblk + srow) * DIM + scol;
  short* Al = As + tid * 8;
  short* Bl = Bs + tid * 8;
  const int xm = lr & 7;                     // fragment-read XOR mask
  for (int k0 = 0; k0 < DIM; k0 += 64) {
#pragma unroll
    for (int j = 0; j < 4; ++j)
      load_lds16(Ag + (long)(j * 32) * DIM + k0, Al + j * 2048);
#pragma unroll
    for (int j = 0; j < 4; ++j)
      load_lds16(Bg + (long)(j * 32) * DIM + k0, Bl + j * 2048);
    asm volatile("s_waitcnt vmcnt(0)" ::: "memory");
    __syncthreads();
#pragma unroll
    for (int kh = 0; kh < 2; ++kh) {
      bf16x8 af[4], bfr[4];
      const int go = ((kh * 4 + quad) ^ xm) * 8;
#pragma unroll
      for (int it = 0; it < 4; ++it)
        af[it] = *(const bf16x8*)(As + (wm + it * 16 + lr) * 64 + go);
#pragma unroll
      for (int jt = 0; jt < 4; ++jt)
        bfr[jt] = *(const bf16x8*)(Bs + (wn + jt * 16 + lr) * 64 + go);
#pragma unroll
      for (int it = 0; it < 4; ++it)
#pragma unroll
        for (int jt = 0; jt < 4; ++jt)
          acc[it][jt] = mfma16(af[it], bfr[jt], acc[it][jt]);
    }
    __syncthreads();
  }
}

__device__ __forceinline__ void tile_store(short* __restrict__ D, int mblk,
                                           int nblk, int tid,
                                           f32x4 (&acc)[4][4]) {
  const int lane = tid & 63, lr = lane & 15, quad = lane >> 4;
  const int wave = tid >> 6, wm = (wave >> 1) * 64, wn = (wave & 1) * 64;
#pragma unroll
  for (int it = 0; it < 4; ++it)
#pragma unroll
    for (int jt = 0; jt < 4; ++jt)
#pragma unroll
      for (int r = 0; r < 4; ++r)
        D[(long)(mblk + wm + it * 16 + quad * 4 + r) * DIM + nblk + wn +
          jt * 16 + lr] = f2b(acc[it][jt][r]);
}

// ----------------------- device sub-routines ------------------------------
__device__ __forceinline__ void do_transpose_job(const void* src, short* dstT,
                                                 int r, int f, int tid,
                                                 char* smem) {
  unsigned short(*tile)[66] = (unsigned short(*)[66])smem;
  unsigned short* dst = (unsigned short*)dstT;
  const int obase = (r / 12) * 64, ibase = (r % 12) * 64;
  const int col = tid & 63, rq = tid >> 6;
#pragma unroll
  for (int rr = 0; rr < 64; rr += 4) {
    const long idx = (long)(obase + rr + rq) * DIM + ibase + col;
    const float v = f ? ((const float*)src)[idx] : b2f(((const short*)src)[idx]);
    tile[rr + rq][col] = (unsigned short)f2b(v);
  }
  __syncthreads();
#pragma unroll
  for (int rr = 0; rr < 64; rr += 4)
    dst[(long)(ibase + rr + rq) * DIM + obase + col] = tile[col][rr + rq];
  __syncthreads();
}

__device__ __forceinline__ void do_bvec_job(const void* Wk_raw,
                                            const void* bq_raw,
                                            float* __restrict__ bvec, int slice,
                                            int f, int tid, float* red) {
  const int jj = slice * 128 + (tid & 127);
  const int half = tid >> 7;
  float s = 0.f;
  if (f) {
    const float* W = (const float*)Wk_raw;
    const float* bq = (const float*)bq_raw;
    for (int o = half; o < DIM; o += 2) s += W[(long)o * DIM + jj] * bq[o];
  } else {
    const short* W = (const short*)Wk_raw;
    const short* bq = (const short*)bq_raw;
    for (int o = half; o < DIM; o += 2) s += b2f(W[(long)o * DIM + jj]) * b2f(bq[o]);
  }
  red[tid] = s;
  __syncthreads();
  if (tid < 128) bvec[jj] = red[tid] + red[tid + 128];
  __syncthreads();
}

__device__ __forceinline__ void do_convert_job(const void* x_raw,
                                               const int* mask,
                                               const float* bvec, short* xb,
                                               float* betas, int n, int f,
                                               int tid) {
  const int lane = tid & 63;
  short* xo = xb + (long)n * DIM;
  float s = 0.f;
  if (f) {
    const f32x4* x4 = (const f32x4*)((const float*)x_raw + (long)n * DIM);
    const f32x4* bv4 = (const f32x4*)bvec;
#pragma unroll
    for (int it = 0; it < 3; ++it) {
      const int idx = it * 64 + lane;
      const f32x4 v = __builtin_nontemporal_load(x4 + idx);  // x read once
      const f32x4 bb = bv4[idx];
      short4v sv = {f2b(v.x), f2b(v.y), f2b(v.z), f2b(v.w)};
      *(short4v*)(xo + idx * 4) = sv;
      s += v.x * bb.x + v.y * bb.y + v.z * bb.z + v.w * bb.w;
    }
  } else {
    const short4v* x4 = (const short4v*)((const short*)x_raw + (long)n * DIM);
    const f32x4* bv4 = (const f32x4*)bvec;
#pragma unroll
    for (int it = 0; it < 3; ++it) {
      const int idx = it * 64 + lane;
      const short4v v = __builtin_nontemporal_load(x4 + idx);
      const f32x4 bb = bv4[idx];
      *(short4v*)(xo + idx * 4) = v;
      s += b2f(v.x) * bb.x + b2f(v.y) * bb.y + b2f(v.z) * bb.z + b2f(v.w) * bb.w;
    }
  }
#pragma unroll
  for (int off = 1; off < 64; off <<= 1) s += __shfl_xor(s, off, 64);
  if (lane == 0) betas[n] = mask[n] ? s * INV_SCALE : -1e30f;
}

__device__ __forceinline__ void score_epilogue(const float* betas, float* l_out,
                                               short* Eb, int b, int mblk,
                                               int nblk, int tid,
                                               f32x4 (&acc)[4][4]) {
  const int lane = tid & 63, lr = lane & 15, quad = lane >> 4;
  const int wave = tid >> 6, wm = (wave >> 1) * 64, wn = (wave & 1) * 64;
  float bet[4];
#pragma unroll
  for (int jt = 0; jt < 4; ++jt)
    bet[jt] = betas[b * S + nblk + wn + jt * 16 + lr];
  float* lrow = l_out + b * S;
#pragma unroll
  for (int it = 0; it < 4; ++it) {
#pragma unroll
    for (int r = 0; r < 4; ++r) {
      const int q = mblk + wm + it * 16 + quad * 4 + r;
      float s = 0.f;
#pragma unroll
      for (int jt = 0; jt < 4; ++jt) {
        float e = __expf(fminf(acc[it][jt][r] * INV_SCALE + bet[jt], 60.f));
        s += e;
        // NT store: E is a write-once stream; keep z/x resident in L2/LLC.
        __builtin_nontemporal_store(
            f2b(e), Eb + (long)q * S + nblk + wn + jt * 16 + lr);
      }
      s += __shfl_xor(s, 1, 64);
      s += __shfl_xor(s, 2, 64);
      s += __shfl_xor(s, 4, 64);
      s += __shfl_xor(s, 8, 64);
      if (lr == 0) atomicAdd(&lrow[q], s);
    }
  }
}

__device__ __forceinline__ void do_reduce_job(const short* Eb, const float* lrow,
                                              float* crow, int q0, int tid) {
  const int k8 = tid * 8;
  float acc[8] = {};
#pragma unroll
  for (int q = q0; q < q0 + 16; ++q) {
    bf16x8 ev =
        __builtin_nontemporal_load((const bf16x8*)(Eb + (long)q * S + k8));
    const float lv = lrow[q];
    const float rq = lv > 0.f ? 1.0f / lv : 0.f;
#pragma unroll
    for (int j = 0; j < 8; ++j) acc[j] += b2f(ev[j]) * rq;
  }
#pragma unroll
  for (int j = 0; j < 8; ++j)
    atomicAdd(&crow[k8 + j], acc[j] * (1.0f / 2048.0f));
}

__device__ __forceinline__ void do_y_job(const short* xb, const float* c,
                                         float* y, int b, int kc, int ic,
                                         int tid) {
  const int i = ic * 256 + tid;
  const int kstart = kc * 128;
  const short* xr = xb + (long)(b * S + kstart) * DIM + i;
  const float* cb = c + b * S + kstart;
  float acc = 0.f;
  for (int k = 0; k < 128; ++k) acc += cb[k] * b2f(xr[(long)k * DIM]);
  atomicAdd(&y[b * DIM + i], acc);
}

__device__ __forceinline__ void do_out_job(const float* y, const void* Wv_raw,
                                           const void* bv_raw, void* out, int w,
                                           int f, int tid) {
  const int lane = tid & 63;
  const int b = w / DIM, o = w % DIM;
  const f32x4* y4 = (const f32x4*)(y + (long)b * DIM);
  float s = 0.f;
  if (f) {
    const f32x4* wr = (const f32x4*)((const float*)Wv_raw + (long)o * DIM);
#pragma unroll
    for (int it = 0; it < 3; ++it) {
      const int idx = it * 64 + lane;
      const f32x4 a = y4[idx], wv = wr[idx];
      s += a.x * wv.x + a.y * wv.y + a.z * wv.z + a.w * wv.w;
    }
  } else {
    const short4v* wr = (const short4v*)((const short*)Wv_raw + (long)o * DIM);
#pragma unroll
    for (int it = 0; it < 3; ++it) {
      const int idx = it * 64 + lane;
      const f32x4 a = y4[idx];
      const short4v wv = wr[idx];
      s += a.x * b2f(wv.x) + a.y * b2f(wv.y) + a.z * b2f(wv.z) + a.w * b2f(wv.w);
    }
  }
#pragma unroll
  for (int off = 1; off < 64; off <<= 1) s += __shfl_xor(s, off, 64);
  if (lane == 0) {
    const float bias = f ? ((const float*)bv_raw)[o] : b2f(((const short*)bv_raw)[o]);
    const float v = s + bias;
    if (f) ((float*)out)[b * DIM + o] = v;
    else ((bf16*)out)[b * DIM + o] = __float2bfloat16(v);
  }
}

// ============================== kernels ===================================
// prep: detects dtype inline (publishes flag), transposes Wq/Wk (288 jobs),
// bvec slices (6 jobs). grid 294.
__global__ __launch_bounds__(256) void prep_kernel(const void* Wq_raw,
                                                   const void* Wk_raw,
                                                   const void* bq_raw,
                                                   const void* x_raw,
                                                   short* T0, short* T1,
                                                   float* bvec,
                                                   int* flag_out) {
  __shared__ __align__(16) char smem[17664];
  int* sflag = (int*)(smem + 17600);
  const unsigned short* xs = (const unsigned short*)x_raw;
  if (threadIdx.x == 0) *sflag = 0;
  __syncthreads();
  int bad = 0;
  for (int i = threadIdx.x; i < 2048; i += 256) {
    int e = (xs[i] >> 7) & 0xFF;
    if (e < 0x60 || e >= 0x9F) bad = 1;
  }
  if (__any(bad) && (threadIdx.x & 63) == 0) atomicOr(sflag, 1);
  __syncthreads();
  const int f = *sflag;
  __syncthreads();
  if (blockIdx.x == 0 && threadIdx.x == 0) *flag_out = f;

  const int bx = blockIdx.x;
  if (bx < 288)
    do_transpose_job(bx < 144 ? Wq_raw : Wk_raw, bx < 144 ? T0 : T1, bx % 144,
                     f, threadIdx.x, smem);
  else
    do_bvec_job(Wk_raw, bq_raw, bvec, bx - 288, f, threadIdx.x,
                (float*)(smem + 16384));
}

// mt_convert: Mt GEMM (36) + x convert/beta (4096) + zero l/c/y (10). 4142.
__global__ __launch_bounds__(256) void mt_convert(const short* WkT,
                                                  const short* WqT, short* Mt,
                                                  const void* x_raw,
                                                  const int* mask,
                                                  const float* bvec, short* xb,
                                                  float* betas, float* lcy,
                                                  const int* flag) {
  __shared__ __align__(16) char smem[32768];
  const int bx = blockIdx.x;
  if (bx < 36) {
    f32x4 acc[4][4] = {};
    tile_kloop(WkT, WqT, (short*)smem, (short*)(smem + 16384), (bx / 6) * 128,
               (bx % 6) * 128, threadIdx.x, acc);
    tile_store(Mt, (bx / 6) * 128, (bx % 6) * 128, threadIdx.x, acc);
  } else if (bx < 4132) {
    const int n = (bx - 36) * 4 + (threadIdx.x >> 6);
    do_convert_job(x_raw, mask, bvec, xb, betas, n, *flag, threadIdx.x);
  } else {
    const int base = (bx - 4132) * 4096;
    for (int i = threadIdx.x; i < 4096; i += 256) {
      const int idx = base + i;
      if (idx < 38912) lcy[idx] = 0.f;
    }
  }
}

__global__ __launch_bounds__(256) void gemm_nt_tiled(const short* A,
                                                     const short* B, short* D) {
  __shared__ __align__(16) char smem[32768];
  f32x4 acc[4][4] = {};
  tile_kloop(A, B, (short*)smem, (short*)(smem + 16384), blockIdx.x * 128,
             blockIdx.y * 128, threadIdx.x, acc);
  tile_store(D, blockIdx.x * 128, blockIdx.y * 128, threadIdx.x, acc);
}

__global__ __launch_bounds__(256) void gemm_score(const short* z, const short* x,
                                                  const float* betas, float* l,
                                                  short* E, int b0) {
  __shared__ __align__(16) char smem[32768];
  const int lb = blockIdx.z, b = b0 + lb;
  f32x4 acc[4][4] = {};
  tile_kloop(z + (long)lb * S * DIM, x + (long)b * S * DIM, (short*)smem,
             (short*)(smem + 16384), blockIdx.x * 128, blockIdx.y * 128,
             threadIdx.x, acc);
  score_epilogue(betas, l, E + (long)lb * S * S, b, blockIdx.x * 128,
                 blockIdx.y * 128, threadIdx.x, acc);
}

__global__ __launch_bounds__(256) void reduce_c(const short* E, const float* l,
                                                float* c, int b0) {
  const int lb = blockIdx.y, b = b0 + lb;
  do_reduce_job(E + (long)lb * S * S, l + b * S, c + b * S, blockIdx.x * 16,
                threadIdx.x);
}

__global__ __launch_bounds__(256) void y_kernel(const short* xb, const float* c,
                                                float* y) {
  do_y_job(xb, c, y, blockIdx.z, blockIdx.y, blockIdx.x, threadIdx.x);
}

__global__ __launch_bounds__(256) void out_kernel(const float* y,
                                                  const void* Wv_raw,
                                                  const void* bv_raw, void* out,
                                                  const int* flag) {
  do_out_job(y, Wv_raw, bv_raw, out, blockIdx.x * 4 + (threadIdx.x >> 6),
             *flag, threadIdx.x);
}

extern "C" void kernel_launch(void* const* d_in, const int* in_sizes, int n_in,
                              void* d_out, int out_size, void* d_ws, size_t ws_size,
                              hipStream_t stream) {
  const void* x_raw = d_in[0];
  const int* mask = (const int*)d_in[1];
  const void* Wq_raw = d_in[2];
  const void* bq_raw = d_in[3];
  const void* Wk_raw = d_in[4];
  // d_in[5] = bk: provably cancels out of the computation.
  const void* Wv_raw = d_in[6];
  const void* bv_raw = d_in[7];

  char* ws = (char*)d_ws;
  short* xb = (short*)(ws);                 //          0 .. 25,165,824
  short* WqT = (short*)(ws + 25165824);     // 1,179,648 B
  short* WkT = (short*)(ws + 26345472);     // 1,179,648 B
  short* Mt = (short*)(ws + 27525120);      // 1,179,648 B  Mt[j,i]=M[i,j]
  float* betas = (float*)(ws + 28704768);   //    65,536 B
  float* bvec = (float*)(ws + 28770304);    //     3,072 B
  float* lcy = (float*)(ws + 28773376);     //   155,648 B (l,c,y contiguous)
  int* flag = (int*)(ws + 28929024);        //        64 B
  short* z = (short*)(ws + 28929088);       // nb * 3,145,728 B

  const size_t fixed = 28929088;
  const size_t zb = 3145728, eb = 8388608;
  int nb = 1;
  if (ws_size >= fixed + 8 * (zb + eb)) nb = 8;
  else if (ws_size >= fixed + 4 * (zb + eb)) nb = 4;
  else if (ws_size >= fixed + 2 * (zb + eb)) nb = 2;
  short* E = (short*)(ws + fixed + (size_t)nb * zb);
  const int rounds = BATCH / nb;

  float* l = lcy;
  float* c = lcy + 16384;
  float* y = lcy + 32768;

  prep_kernel<<<294, 256, 0, stream>>>(Wq_raw, Wk_raw, bq_raw, x_raw, WqT, WkT,
                                       bvec, flag);
  mt_convert<<<4142, 256, 0, stream>>>(WkT, WqT, Mt, x_raw, mask, bvec, xb,
                                       betas, lcy, flag);
  for (int r = 0; r < rounds; ++r) {
    const int b0 = r * nb;
    gemm_nt_tiled<<<dim3(nb * 16, 6), 256, 0, stream>>>(
        xb + (long)b0 * S * DIM, Mt, z);
    gemm_score<<<dim3(16, 16, nb), 256, 0, stream>>>(z, xb, betas, l, E, b0);
    reduce_c<<<dim3(128, nb), 256, 0, stream>>>(E, l, c, b0);
  }
  y_kernel<<<dim3(3, 16, 8), 256, 0, stream>>>(xb, c, y);
  out_kernel<<<1536, 256, 0, stream>>>(y, Wv_raw, bv_raw, d_out, flag);
}